// Round 5
// baseline (488.056 us; speedup 1.0000x reference)
//
#include <hip/hip_runtime.h>

#define NCH 6
#define NX 32
#define PLANE 1024
#define NCELL (NX * PLANE)
#define CH_STRIDE NCELL
#define STEP_STRIDE (NCH * NCELL)   // 196608 floats per history slice
#define NBLOCKS 128                  // x-plane (32) x y-stripes (4)
#define NTHREADS 256                 // 8 y-rows x 32 z
#define NWAVES 4

// ws layout after phi_a|phi_b. Slots: one 64B line per block.
#define F_TFREEZE 1
#define F_PARITY 2
#define F_SLOTS 32                   // slot b at flags[F_SLOTS + b*16]

__device__ __forceinline__ float ld_coh(const float* p) {
    return __hip_atomic_load(p, __ATOMIC_RELAXED, __HIP_MEMORY_SCOPE_SYSTEM);
}
__device__ __forceinline__ void st_coh(float* p, float v) {
    __hip_atomic_store(p, v, __ATOMIC_RELAXED, __HIP_MEMORY_SCOPE_SYSTEM);
}
__device__ __forceinline__ int ld_cohi(const int* p) {
    return __hip_atomic_load(p, __ATOMIC_RELAXED, __HIP_MEMORY_SCOPE_SYSTEM);
}
__device__ __forceinline__ void st_cohi(int* p, int v) {
    __hip_atomic_store(p, v, __ATOMIC_RELAXED, __HIP_MEMORY_SCOPE_SYSTEM);
}

// Per-wave arrive: release-add on an LDS counter (monotonic, 4 adds/barrier).
// The workgroup-release emits s_waitcnt vmcnt(0) lgkmcnt(0) for the wave ->
// its sc1 phi stores are ack'd at L3 and its LDS tile writes complete BEFORE
// the counter bumps. History stores are issued by the caller AFTER this, so
// their slow HBM acks stay out of the barrier's critical path.
// Last-arriving wave publishes slot = (want<<1) | block_done.
__device__ __forceinline__ void barrier_arrive(int want, int bx, int tid,
                                               int* cnt, int* dflag, int* flags) {
    if ((tid & 63) == 0) {
        const int ret = __hip_atomic_fetch_add(cnt, 1, __ATOMIC_RELEASE,
                                               __HIP_MEMORY_SCOPE_WORKGROUP);
        if (ret == NWAVES * want - 1) {
            const int df = __hip_atomic_load(dflag, __ATOMIC_RELAXED,
                                             __HIP_MEMORY_SCOPE_WORKGROUP);
            st_cohi(&flags[F_SLOTS + bx * 16], (want << 1) | df);
        }
    }
}

// All-to-all wait: wave 0 polls all 128 slots (2/lane); waves 1..3 spin on an
// LDS gen. Done bit is epoch-matched ((v>>1)==want): a tripped block freezes
// its slot at its trip epoch, so every block observes done at the SAME
// barrier; blocks can be at most one epoch ahead (cnt gating), and their
// future-epoch bits are ignored -> no premature freeze, no deadlock.
// Slot poison (0xAAAAAAAA, negative) fails (v>>1)>=want -> bootstrap-safe.
__device__ __forceinline__ int barrier_wait(int want, int tid,
                                            int* gen, int* flags) {
    int done;
    if (tid < 64) {
        const int* s0 = &flags[F_SLOTS + tid * 16];
        const int* s1 = &flags[F_SLOTS + (tid + 64) * 16];
        for (;;) {
            const int a = ld_cohi(s0);
            const int b = ld_cohi(s1);
            const bool pass = ((a >> 1) >= want) && ((b >> 1) >= want);
            if (__ballot(pass) == ~0ull) {
                const int bit = (((a >> 1) == want) & (a & 1)) |
                                (((b >> 1) == want) & (b & 1));
                done = (__ballot(bit != 0) != 0ull);
                break;
            }
            __builtin_amdgcn_s_sleep(2);
        }
        if (tid == 0)
            __hip_atomic_store(gen, (want << 1) | done, __ATOMIC_RELEASE,
                               __HIP_MEMORY_SCOPE_WORKGROUP);
    } else {
        int g;
        for (;;) {
            g = __hip_atomic_load(gen, __ATOMIC_ACQUIRE,
                                  __HIP_MEMORY_SCOPE_WORKGROUP);
            if ((g >> 1) >= want) break;
            __builtin_amdgcn_s_sleep(2);
        }
        done = g & 1;
    }
    // No trailing __syncthreads needed: intra-block skew is bounded to one
    // barrier by the cnt gating, and the LDS tile is ping-ponged.
    return done;
}

// Block = (x-plane, 8-row y-stripe). z/y neighbors intra-block via LDS
// (boundary y-rows fall back to sc1 global); x+-1 planes via sc1 global.
__global__ void __launch_bounds__(NTHREADS, 1)
BEMNA_V7_2_PhaseSpace_44117904064519_kernel(
    const float* __restrict__ D,
    const int* __restrict__ sx_p, const int* __restrict__ sy_p,
    const int* __restrict__ sz_p, const int* __restrict__ ex_p,
    const int* __restrict__ ey_p, const int* __restrict__ ez_p,
    const int* __restrict__ maxit_p,
    float* __restrict__ out,
    float* __restrict__ phi_a,
    float* __restrict__ phi_b,
    int* __restrict__ flags)
{
    __shared__ float tile[2][NCH][NTHREADS];  // ping-pong own-tile, 12 KB
    __shared__ int lds_cnt, lds_gen, lds_done;

    const int tid = (int)threadIdx.x;
    const int bx  = (int)blockIdx.x;          // 0..127
    const int x   = bx >> 2;                  // plane
    const int s   = bx & 3;                   // y-stripe
    const int yl  = tid >> 5;                 // 0..7
    const int z   = tid & 31;
    const int y   = (s << 3) + yl;
    const int cell = (x << 10) + (y << 5) + z;

    const int sx = *sx_p, sy = *sy_p, sz = *sz_p;
    const int ex = *ex_p, ey = *ey_p, ez = *ez_p;
    const int maxit = *maxit_p;
    const bool is_seed   = (cell == ((sx << 10) | (sy << 5) | sz));
    const bool is_target = (cell == ((ex << 10) | (ey << 5) | ez));

    // o=0 reads (x-1); o=1 (x+1); o=2 (y-1); o=3 (y+1); o=4 (z-1); o=5 (z+1)
    const int  nbg[NCH] = { cell - PLANE, cell + PLANE, cell - 32, cell + 32, cell - 1, cell + 1 };
    const bool ok[NCH]  = { x >= 1, x <= 30, y >= 1, y <= 30, z >= 1, z <= 30 };

    // D step-invariant: hoist 36 coefficients (zeroed where out-of-bounds,
    // so boundary contributions fold to clip(0)=0 like the reference)
    float dreg[NCH][NCH];
#pragma unroll
    for (int o = 0; o < NCH; ++o)
#pragma unroll
        for (int i = 0; i < NCH; ++i)
            dreg[o][i] = ok[o] ? D[(size_t)(o * NCH + i) * CH_STRIDE + nbg[o]] + 0.95f : 0.0f;

    // ---- init ----
    if (tid == 0) { lds_cnt = 0; lds_gen = 0; lds_done = 0; }
    float myv[NCH];
    float* cur = phi_a;
    float* nxt = phi_b;
    int buf = 0;
    const float init_v = is_seed ? 1.0f : 0.0f;
#pragma unroll
    for (int o = 0; o < NCH; ++o) {
        myv[o] = init_v;
        st_coh(&cur[o * CH_STRIDE + cell], init_v);
        tile[0][o][tid] = init_v;
    }
    __syncthreads();                          // lds_cnt=0 visible before adds
    barrier_arrive(1, bx, tid, &lds_cnt, &lds_done, flags);
    (void)barrier_wait(1, tid, &lds_gen, flags);

    int t = 0, done = 0;
    for (; t < maxit; ++t) {
        if (done) {
            // freeze observed at barrier t-1: slice t = frozen phi, then stop
            float* outp = out + (size_t)t * STEP_STRIDE + cell;
#pragma unroll
            for (int o = 0; o < NCH; ++o) outp[o * CH_STRIDE] = myv[o];
            break;
        }

        // gather neighbors: global sc1 (x+-, y-halo) issued first
        const float (*L)[NTHREADS] = tile[buf];
        float phx0[NCH], phx1[NCH], phy0[NCH], phy1[NCH];
#pragma unroll
        for (int i = 0; i < NCH; ++i) {
            phx0[i] = ok[0] ? ld_coh(&cur[i * CH_STRIDE + cell - PLANE]) : 0.0f;
            phx1[i] = ok[1] ? ld_coh(&cur[i * CH_STRIDE + cell + PLANE]) : 0.0f;
        }
        if (yl == 0) {
#pragma unroll
            for (int i = 0; i < NCH; ++i)
                phy0[i] = ok[2] ? ld_coh(&cur[i * CH_STRIDE + cell - 32]) : 0.0f;
        } else {
#pragma unroll
            for (int i = 0; i < NCH; ++i) phy0[i] = L[i][tid - 32];
        }
        if (yl == 7) {
#pragma unroll
            for (int i = 0; i < NCH; ++i)
                phy1[i] = ok[3] ? ld_coh(&cur[i * CH_STRIDE + cell + 32]) : 0.0f;
        } else {
#pragma unroll
            for (int i = 0; i < NCH; ++i) phy1[i] = L[i][tid + 32];
        }

        float v[NCH];
        {
            float a0 = 0.f, a1 = 0.f, a2 = 0.f, a3 = 0.f, a4 = 0.f, a5 = 0.f;
#pragma unroll
            for (int i = 0; i < NCH; ++i) {
                a0 = fmaf(dreg[0][i], phx0[i], a0);
                a1 = fmaf(dreg[1][i], phx1[i], a1);
                a2 = fmaf(dreg[2][i], phy0[i], a2);
                a3 = fmaf(dreg[3][i], phy1[i], a3);
                a4 = fmaf(dreg[4][i], (z >= 1)  ? L[i][tid - 1] : 0.0f, a4);
                a5 = fmaf(dreg[5][i], (z <= 30) ? L[i][tid + 1] : 0.0f, a5);
            }
            v[0] = fminf(fmaxf(a0, 0.f), 1.f);
            v[1] = fminf(fmaxf(a1, 0.f), 1.f);
            v[2] = fminf(fmaxf(a2, 0.f), 1.f);
            v[3] = fminf(fmaxf(a3, 0.f), 1.f);
            v[4] = fminf(fmaxf(a4, 0.f), 1.f);
            v[5] = fminf(fmaxf(a5, 0.f), 1.f);
        }

        // publish phi_{t+1}: sc1 global + own LDS tile
#pragma unroll
        for (int o = 0; o < NCH; ++o) {
            st_coh(&nxt[o * CH_STRIDE + cell], v[o]);
            tile[buf ^ 1][o][tid] = v[o];
        }
        if (is_target && (v[0] + v[1] + v[2] + v[3] + v[4] + v[5] > 0.01f))
            __hip_atomic_store(&lds_done, 1, __ATOMIC_RELAXED,
                               __HIP_MEMORY_SCOPE_WORKGROUP);

        barrier_arrive(t + 2, bx, tid, &lds_cnt, &lds_done, flags);

        // history slice t (pre-update phi) — issued AFTER arrive so its HBM
        // store-acks overlap the barrier spin instead of gating it
        float* outp = out + (size_t)t * STEP_STRIDE + cell;
#pragma unroll
        for (int o = 0; o < NCH; ++o) outp[o * CH_STRIDE] = myv[o];

        done = barrier_wait(t + 2, tid, &lds_gen, flags);

        float* tmp = cur; cur = nxt; nxt = tmp;
        buf ^= 1;
#pragma unroll
        for (int o = 0; o < NCH; ++o) myv[o] = v[o];
    }

    // stepper wrote slices 0..t_freeze; fill covers the rest
    const int t_freeze = (t < maxit) ? t : (maxit - 1);
    if (bx == 0 && tid == 0) {
        flags[F_TFREEZE] = t_freeze;
        flags[F_PARITY]  = t_freeze & 1;   // phi_{t_freeze} lives in parity?phi_b:phi_a
    }
}

// Fat fill kernel: slices t_freeze+1 .. maxit-1 all equal the frozen phi.
__global__ void fill_kernel(const int* __restrict__ flags,
                            const float* __restrict__ phi_a,
                            const float* __restrict__ phi_b,
                            float4* __restrict__ out,
                            int total4)
{
    const int idx4 = blockIdx.x * blockDim.x + threadIdx.x;
    if (idx4 >= total4) return;
    const int t_freeze = flags[F_TFREEZE];
    const int t = idx4 / (STEP_STRIDE / 4);
    if (t <= t_freeze) return;
    const int r4 = idx4 - t * (STEP_STRIDE / 4);
    const float4* frozen = (const float4*)(flags[F_PARITY] ? phi_b : phi_a);
    out[idx4] = frozen[r4];
}

extern "C" void kernel_launch(void* const* d_in, const int* in_sizes, int n_in,
                              void* d_out, int out_size, void* d_ws, size_t ws_size,
                              hipStream_t stream)
{
    const float* D   = (const float*)d_in[0];
    const int* sx    = (const int*)d_in[1];
    const int* sy    = (const int*)d_in[2];
    const int* sz    = (const int*)d_in[3];
    const int* ex    = (const int*)d_in[4];
    const int* ey    = (const int*)d_in[5];
    const int* ez    = (const int*)d_in[6];
    const int* maxit = (const int*)d_in[7];
    float* out = (float*)d_out;

    float* phi_a = (float*)d_ws;
    float* phi_b = phi_a + (size_t)NCH * NCELL;
    int* flags   = (int*)(phi_b + (size_t)NCH * NCELL);

    // 128 blocks x 256 threads: 4x the CUs of R4 (per-CU BW was the binding
    // constraint: 2.3 MB/step / (32 CU x 24.6 GB/s) = 2.9 us = observed).
    // Non-cooperative: co-residency by capacity (128 blocks << 256 CUs @ 1/CU).
    BEMNA_V7_2_PhaseSpace_44117904064519_kernel<<<dim3(NBLOCKS), dim3(NTHREADS), 0, stream>>>(
        D, sx, sy, sz, ex, ey, ez, maxit, out, phi_a, phi_b, flags);

    const int total4 = out_size / 4;
    const int fill_blocks = (total4 + 255) / 256;
    fill_kernel<<<dim3(fill_blocks), dim3(256), 0, stream>>>(
        flags, phi_a, phi_b, (float4*)out, total4);
}